// Round 5
// baseline (282.435 us; speedup 1.0000x reference)
//
#include <hip/hip_runtime.h>
#include <math.h>

// Problem constants
constexpr int Bb = 4, Ll = 2048, Ss = 2048, Hh = 16, Ee = 64;
constexpr float S2E  = 0.125f * 1.44269504088896341f;  // SCALE * log2(e)
constexpr float EPS2 = 1e-8f * S2E * S2E;
constexpr float INV_CNT = 1.0f / (4.0f * 16.0f * 2048.0f * 2048.0f);
// scsum accumulates score*log2(e); convert back with ln2
constexpr float SUM_SCALE = INV_CNT * 0.69314718055994531f;

typedef __attribute__((ext_vector_type(8)))  short short8;   // 8 x bf16 bits
typedef __attribute__((ext_vector_type(4)))  float floatx4;
typedef __attribute__((ext_vector_type(16))) float floatx16; // 32x32 MFMA C/D

#define MFMA32 __builtin_amdgcn_mfma_f32_32x32x16_bf16

// async global(16B/lane) -> LDS (wave-uniform dst base + lane*16)
#define GLL(gp, lp_)                                                       \
  __builtin_amdgcn_global_load_lds(                                        \
      (const __attribute__((address_space(1))) unsigned int*)(gp),         \
      (__attribute__((address_space(3))) unsigned int*)(lp_), 16, 0, 0)

__device__ __forceinline__ unsigned bfrnd(float f) {  // RNE, bf16 in high 16
  unsigned u = __builtin_bit_cast(unsigned, f);
  return u + 0x7fffu + ((u >> 16) & 1u);
}
__device__ __forceinline__ float sq4(float4 v) {
  return v.x * v.x + v.y * v.y + v.z * v.z + v.w * v.w;
}
__device__ __forceinline__ float4 mul4(float4 v, float s) {
  float4 r; r.x = v.x * s; r.y = v.y * s; r.z = v.z * s; r.w = v.w * s;
  return r;
}
__device__ __forceinline__ short8 pack8(float4 x, float4 y) {
  union { short8 s; unsigned u[4]; } r;
  r.u[0] = __builtin_amdgcn_perm(bfrnd(x.y), bfrnd(x.x), 0x07060302u);
  r.u[1] = __builtin_amdgcn_perm(bfrnd(x.w), bfrnd(x.z), 0x07060302u);
  r.u[2] = __builtin_amdgcn_perm(bfrnd(y.y), bfrnd(y.x), 0x07060302u);
  r.u[3] = __builtin_amdgcn_perm(bfrnd(y.w), bfrnd(y.z), 0x07060302u);
  return r.s;
}
// v_permlane32_swap_b32: a.hi32 <-> b.lo32.
__device__ __forceinline__ void pl32swap(unsigned &a, unsigned &b) {
  asm("v_permlane32_swap_b32 %0, %1" : "+v"(a), "+v"(b));
}

// ---------- Pre-pass: K->bf16 [bh][s][e], V->bf16^T [bh][e][s] (LDS-transposed,
// coalesced 128B output segments), kn2 ----------
__global__ __launch_bounds__(256) void geom_pre_kernel(
    const float* __restrict__ Kg, const float* __restrict__ Vg,
    short* __restrict__ Kbf, short* __restrict__ Vtg,
    float* __restrict__ kn2g, float* __restrict__ sumg) {
  __shared__ __align__(16) short vsm[64 * 66];  // [e-row][66 shorts] 132B stride
  const int tid = threadIdx.x, bid = blockIdx.x;
  const int st = bid & 31, h = (bid >> 5) & 15, b = bid >> 9;
  const int s0 = st * 64, bh = b * 16 + h;
  if (bid == 0 && tid == 0) *sumg = 0.0f;

  // K + kn2 (coalesced float4 reads, b128 bf16 writes)
  const int r64 = tid >> 2, ec = (tid & 3) * 16;
  const float4* kp = (const float4*)(Kg + (((size_t)b * Ss + s0 + r64) * Hh + h) * Ee + ec);
  float4 k0 = kp[0], k1 = kp[1], k2 = kp[2], k3 = kp[3];
  float kn = sq4(k0) + sq4(k1) + sq4(k2) + sq4(k3);
  kn += __shfl_xor(kn, 1);
  kn += __shfl_xor(kn, 2);
  if ((tid & 3) == 0) kn2g[(size_t)bh * Ss + s0 + r64] = kn;
  short* ko = Kbf + ((size_t)bh * Ss + s0 + r64) * Ee + ec;
  *(short8*)(ko)     = pack8(k0, k1);
  *(short8*)(ko + 8) = pack8(k2, k3);

  // V: read 4 s-rows x 4 e-cols, convert, transpose via LDS
  const int sq = tid >> 4, eq = tid & 15;
  const float* vb = Vg + (((size_t)b * Ss + s0 + sq * 4) * Hh + h) * Ee + eq * 4;
  float4 r0 = *(const float4*)(vb);
  float4 r1 = *(const float4*)(vb + Hh * Ee);
  float4 r2 = *(const float4*)(vb + 2 * Hh * Ee);
  float4 r3 = *(const float4*)(vb + 3 * Hh * Ee);
#pragma unroll
  for (int j = 0; j < 4; ++j) {
    unsigned lo = __builtin_amdgcn_perm(bfrnd((&r1.x)[j]), bfrnd((&r0.x)[j]), 0x07060302u);
    unsigned hh = __builtin_amdgcn_perm(bfrnd((&r3.x)[j]), bfrnd((&r2.x)[j]), 0x07060302u);
    short* row = vsm + (eq * 4 + j) * 66 + sq * 4;  // e-row, s = sq*4..+3
    *(unsigned*)(row)     = lo;
    *(unsigned*)(row + 2) = hh;
  }
  __syncthreads();
  // write out: thread -> e-row = tid>>2, 32B s-chunk = (tid&3)*16 shorts
  const int e = tid >> 2, sc = (tid & 3) * 16;
  const short* rr = vsm + e * 66 + sc;
  uint4 a, c;
  a.x = *(const unsigned*)(rr + 0);  a.y = *(const unsigned*)(rr + 2);
  a.z = *(const unsigned*)(rr + 4);  a.w = *(const unsigned*)(rr + 6);
  c.x = *(const unsigned*)(rr + 8);  c.y = *(const unsigned*)(rr + 10);
  c.z = *(const unsigned*)(rr + 12); c.w = *(const unsigned*)(rr + 14);
  short* vo = Vtg + ((size_t)bh * Ee + e) * Ss + s0 + sc;
  *(uint4*)(vo)     = a;
  *(uint4*)(vo + 8) = c;
}

// ---------- Main: flash attention, 32x32 MFMA, S^T orientation, BK=64 ----------
// 4 waves x 32 l-rows = 128 rows/block, grid 1024 (4 blocks/CU).
// Round-5: BK=64 with TWO independent 32x32 s-subtiles per iteration.
// Issue order QK(d0), QK(d1), sm(d0), PV(d0), sm(d1), PV(d1): softmax VALU of
// one subtile executes under the MFMA shadow of the other -> intra-wave
// MFMA/VALU overlap (the serial QK->sm->PV chain was the round-4 stall).
// Double-buffered 8KB K + 8KB V tiles; vmcnt(0)-before-barrier is free here
// (loads issued a full ~1700cy iteration ahead, L2-hit after XCD swizzle).
// LDS (bytes): K 2x8192 [0,16384)  V^T 2x8192 [16384,32768)  kn2 [32768,40960)
// = 40KB -> exactly 4 blocks/CU (160KB).
constexpr int KB0 = 0, VB0 = 16384, KN2 = 32768;

__global__ __launch_bounds__(256, 4) void geom_attn_kernel(
    const float* __restrict__ Qg, const short* __restrict__ Kbf,
    const short* __restrict__ Vtg, const float* __restrict__ kn2g,
    float* __restrict__ outg, float* __restrict__ sumg) {
  __shared__ __align__(16) char smem[40960];

  const int tid = threadIdx.x, w = tid >> 6, lane = tid & 63;
  const int l31 = lane & 31, hi = lane >> 5;
  // XCD swizzle: 128 consecutive works (8 full bh-groups) per XCD.
  const int bid = blockIdx.x;
  const int wk = ((bid & 7) << 7) | (bid >> 3);
  const int lt = wk & 15, h = (wk >> 4) & 15, b = wk >> 8;
  const int bh = b * 16 + h;
  const int l0w = lt * 128 + w * 32;

  // Q B-frags (col = l31, k-slice = ks*16 + hi*8 + 0..7), pre-scaled by S2E
  short8 qB[4];
  float qn2v;
  {
    const float* qrow = Qg + (((size_t)b * Ll + l0w + l31) * Hh + h) * Ee;
    float qn = 0.f;
#pragma unroll
    for (int ks = 0; ks < 4; ++ks) {
      float4 a0 = mul4(*(const float4*)(qrow + ks * 16 + hi * 8), S2E);
      float4 a1 = mul4(*(const float4*)(qrow + ks * 16 + hi * 8 + 4), S2E);
      qn += sq4(a0) + sq4(a1);
      qB[ks] = pack8(a0, a1);
    }
    qn += __shfl_xor(qn, 32);  // other hi half holds the other 32 elems
    qn2v = qn;
  }

  // staging source pointers (XOR-swizzled 16B granules; LDS dst stays linear,
  // source granule pre-swizzled -> read-side XOR matches)
  const int rK = tid >> 3, pK = tid & 7;
  const char* kSrc = (const char*)Kbf + (size_t)bh * (Ss * 128)
                     + rK * 128 + ((pK ^ (rK & 7)) * 16);          // +8192/tile
  const char* vSrc = (const char*)Vtg + (size_t)bh * (Ss * 128)
                     + rK * (Ss * 2) + ((pK ^ (rK & 7)) * 16);     // +128/tile
  char* kDstW = smem + KB0 + w * 1024;  // + buf*8192 (+4096 for rows 32..63)
  char* vDstW = smem + VB0 + w * 1024;

  // kn2 -> LDS once (8 KB; lgkm-domain broadcast reads thereafter)
  {
    const char* knSrc = (const char*)kn2g + (size_t)bh * 8192 + (size_t)tid * 16;
    GLL(knSrc, smem + KN2 + w * 1024);
    GLL(knSrc + 4096, smem + KN2 + w * 1024 + 4096);
  }
  // prologue: stage tile 0 into buffer 0 (K rows 0-31, 32-63; V e-rows 0-31, 32-63)
  GLL(kSrc, kDstW);
  GLL(kSrc + 4096, kDstW + 4096);
  GLL(vSrc, vDstW);
  GLL(vSrc + 32 * (Ss * 2), vDstW + 4096);
  kSrc += 8192; vSrc += 128;

  floatx16 o[2] = {};
  float lp = 0.f, scsum = 0.f;

  const int kSwz = l31 & 7;  // K row = 8 granules; read granule (2ks+hi)^kSwz
  const int vSwz = l31 & 7;  // V row = 8 granules; read granule (sb*4+2ks2+hi)^vSwz

  // softmax of one 32x32 S^T subtile -> bf16 PV A-frags (in-register, permlane)
  auto sm = [&](const floatx16& dd, int knByte, short8& paA, short8& paB) {
    unsigned pk[4][2];
#pragma unroll
    for (int q = 0; q < 4; ++q) {
      float4 knq = *(const float4*)(smem + knByte + q * 32 + hi * 16);
      float pe[4], rt4[4];
#pragma unroll
      for (int r = 0; r < 4; ++r) {
        float dot = dd[4 * q + r];
        float w2 = fmaf(-dot, dot, qn2v * (&knq.x)[r]);
        w2 = fmaxf(w2, EPS2);
        rt4[r] = __builtin_amdgcn_sqrtf(w2);      // = score*log2(e)
        pe[r]  = __builtin_amdgcn_exp2f(rt4[r]);  // exp(score), no max-sub
      }
      scsum += (rt4[0] + rt4[1]) + (rt4[2] + rt4[3]);
      lp    += (pe[0] + pe[1]) + (pe[2] + pe[3]);
      pk[q][0] = __builtin_amdgcn_perm(__builtin_bit_cast(unsigned, pe[1]),
                                       __builtin_bit_cast(unsigned, pe[0]), 0x07060302u);
      pk[q][1] = __builtin_amdgcn_perm(__builtin_bit_cast(unsigned, pe[3]),
                                       __builtin_bit_cast(unsigned, pe[2]), 0x07060302u);
    }
    pl32swap(pk[0][0], pk[1][0]);
    pl32swap(pk[0][1], pk[1][1]);
    pl32swap(pk[2][0], pk[3][0]);
    pl32swap(pk[2][1], pk[3][1]);
    union { unsigned u[4]; short8 s; } A, B;
    A.u[0] = pk[0][0]; A.u[1] = pk[0][1]; A.u[2] = pk[1][0]; A.u[3] = pk[1][1];
    B.u[0] = pk[2][0]; B.u[1] = pk[2][1]; B.u[2] = pk[3][0]; B.u[3] = pk[3][1];
    paA = A.s; paB = B.s;
  };

  asm volatile("s_waitcnt vmcnt(0)" ::: "memory");  // kn2 + tile 0 resident
  __builtin_amdgcn_s_barrier();
  asm volatile("" ::: "memory");

  for (int it = 0; it < 32; ++it) {
    const int p = it & 1;
    if (it) {
      asm volatile("s_waitcnt vmcnt(0)" ::: "memory");  // tile it resident
      __builtin_amdgcn_s_barrier();
      asm volatile("" ::: "memory");
    }
    if (it < 31) {  // prefetch tile it+1 into buf p^1 (issued after barrier:
                    // all waves finished reading buf p^1 = tile it-1)
      const int pn = p ^ 1;
      GLL(kSrc, kDstW + pn * 8192);
      GLL(kSrc + 4096, kDstW + pn * 8192 + 4096);
      GLL(vSrc, vDstW + pn * 8192);
      GLL(vSrc + 32 * (Ss * 2), vDstW + pn * 8192 + 4096);
      kSrc += 8192; vSrc += 128;
    }
    const char* Kb = smem + KB0 + p * 8192;
    const char* Vb = smem + VB0 + p * 8192;
    const int knByte = KN2 + it * 256;

    // ---- QK subtile 0 (s rows l31) ----
    short8 ka0 = *(const short8*)(Kb + l31 * 128 + (((0 + hi) ^ kSwz) * 16));
    short8 ka1 = *(const short8*)(Kb + l31 * 128 + (((2 + hi) ^ kSwz) * 16));
    short8 ka2 = *(const short8*)(Kb + l31 * 128 + (((4 + hi) ^ kSwz) * 16));
    short8 ka3 = *(const short8*)(Kb + l31 * 128 + (((6 + hi) ^ kSwz) * 16));
    __builtin_amdgcn_s_setprio(1);
    floatx16 d0 = {};
    d0 = MFMA32(ka0, qB[0], d0, 0, 0, 0);
    d0 = MFMA32(ka1, qB[1], d0, 0, 0, 0);
    d0 = MFMA32(ka2, qB[2], d0, 0, 0, 0);
    d0 = MFMA32(ka3, qB[3], d0, 0, 0, 0);
    __builtin_amdgcn_s_setprio(0);

    // ---- QK subtile 1 (s rows 32+l31) ----
    short8 kb0 = *(const short8*)(Kb + 4096 + l31 * 128 + (((0 + hi) ^ kSwz) * 16));
    short8 kb1 = *(const short8*)(Kb + 4096 + l31 * 128 + (((2 + hi) ^ kSwz) * 16));
    short8 kb2 = *(const short8*)(Kb + 4096 + l31 * 128 + (((4 + hi) ^ kSwz) * 16));
    short8 kb3 = *(const short8*)(Kb + 4096 + l31 * 128 + (((6 + hi) ^ kSwz) * 16));
    __builtin_amdgcn_s_setprio(1);
    floatx16 d1 = {};
    d1 = MFMA32(kb0, qB[0], d1, 0, 0, 0);
    d1 = MFMA32(kb1, qB[1], d1, 0, 0, 0);
    d1 = MFMA32(kb2, qB[2], d1, 0, 0, 0);
    d1 = MFMA32(kb3, qB[3], d1, 0, 0, 0);
    __builtin_amdgcn_s_setprio(0);

    // ---- softmax(d0): VALU runs under d1's MFMA shadow ----
    short8 paA, paB;
    sm(d0, knByte, paA, paB);

    // ---- PV(d0): V frags subtile 0 (granules 0..3) ----
    short8 vb00 = *(const short8*)(Vb + l31 * 128 + (((0 + hi) ^ vSwz) * 16));
    short8 vb01 = *(const short8*)(Vb + l31 * 128 + (((2 + hi) ^ vSwz) * 16));
    short8 vb10 = *(const short8*)(Vb + (32 + l31) * 128 + (((0 + hi) ^ vSwz) * 16));
    short8 vb11 = *(const short8*)(Vb + (32 + l31) * 128 + (((2 + hi) ^ vSwz) * 16));
    __builtin_amdgcn_s_setprio(1);
    o[0] = MFMA32(paA, vb00, o[0], 0, 0, 0);
    o[0] = MFMA32(paB, vb01, o[0], 0, 0, 0);
    o[1] = MFMA32(paA, vb10, o[1], 0, 0, 0);
    o[1] = MFMA32(paB, vb11, o[1], 0, 0, 0);
    __builtin_amdgcn_s_setprio(0);

    // ---- softmax(d1): VALU runs under PV(d0)'s MFMA shadow ----
    sm(d1, knByte + 128, paA, paB);

    // ---- PV(d1): V frags subtile 1 (granules 4..7) ----
    vb00 = *(const short8*)(Vb + l31 * 128 + (((4 + hi) ^ vSwz) * 16));
    vb01 = *(const short8*)(Vb + l31 * 128 + (((6 + hi) ^ vSwz) * 16));
    vb10 = *(const short8*)(Vb + (32 + l31) * 128 + (((4 + hi) ^ vSwz) * 16));
    vb11 = *(const short8*)(Vb + (32 + l31) * 128 + (((6 + hi) ^ vSwz) * 16));
    __builtin_amdgcn_s_setprio(1);
    o[0] = MFMA32(paA, vb00, o[0], 0, 0, 0);
    o[0] = MFMA32(paB, vb01, o[0], 0, 0, 0);
    o[1] = MFMA32(paA, vb10, o[1], 0, 0, 0);
    o[1] = MFMA32(paB, vb11, o[1], 0, 0, 0);
    __builtin_amdgcn_s_setprio(0);
  }
  // nothing outstanding: last GLL waited at it=31 top; LDS reads are per-wave.

  // softmax denominator: fold the 2 hi replicas; lanes 0..31 hold lp[l31]
  lp += __shfl_xor(lp, 32);
  float lpinv = 1.0f / lp;

  // epilogue: lane (e31=l31, hi) holds O[row][et*32+e31], row=(r&3)+8*(r>>2)+4*hi
#pragma unroll
  for (int r = 0; r < 16; ++r) {
    const int row = (r & 3) + 8 * (r >> 2) + 4 * hi;
    float inv = __shfl(lpinv, row);
    float* orow = outg + (((size_t)b * Ll + l0w + row) * Hh + h) * Ee + l31;
    orow[0]  = o[0][r] * inv;
    orow[32] = o[1][r] * inv;
  }

  // mean|scores|: wave-reduce, one atomic per wave
  scsum += __shfl_xor(scsum, 1);
  scsum += __shfl_xor(scsum, 2);
  scsum += __shfl_xor(scsum, 4);
  scsum += __shfl_xor(scsum, 8);
  scsum += __shfl_xor(scsum, 16);
  scsum += __shfl_xor(scsum, 32);
  if (lane == 0) atomicAdd(sumg, scsum * SUM_SCALE);
}

extern "C" void kernel_launch(void* const* d_in, const int* in_sizes, int n_in,
                              void* d_out, int out_size, void* d_ws, size_t ws_size,
                              hipStream_t stream) {
  const float* Q = (const float*)d_in[0];
  const float* K = (const float*)d_in[1];
  const float* V = (const float*)d_in[2];
  float* out   = (float*)d_out;
  float* sumsc = out + (size_t)Bb * Ll * Hh * Ee;

  // workspace: Kbf 16.78 MB | Vt 16.78 MB | kn2 0.52 MB (ws >= 34.1 MB)
  short* Kbf = (short*)d_ws;
  short* Vtg = Kbf + (size_t)Bb * Hh * Ss * Ee;
  float* kn2 = (float*)(Vtg + (size_t)Bb * Hh * Ee * Ss);

  hipLaunchKernelGGL(geom_pre_kernel, dim3(Bb * Hh * (Ss / 64)), dim3(256), 0,
                     stream, K, V, Kbf, Vtg, kn2, sumsc);
  hipLaunchKernelGGL(geom_attn_kernel, dim3(Bb * Hh * (Ll / 128)), dim3(256), 0,
                     stream, Q, Kbf, Vtg, kn2, out, sumsc);
}